// Round 1
// baseline (570.030 us; speedup 1.0000x reference)
//
#include <hip/hip_runtime.h>
#include <math.h>

#define B_  2
#define L_  2048
#define D_  1024
#define H_  16
#define HD_ 64
#define DF_ 4096
#define NR_ 4096   // B_*L_

typedef __bf16 bf16_t;
typedef bf16_t bf16x8 __attribute__((ext_vector_type(8)));
typedef float  f32x4  __attribute__((ext_vector_type(4)));
typedef unsigned short u16;
typedef u16 u16x8 __attribute__((ext_vector_type(8)));
typedef u16 u16x4 __attribute__((ext_vector_type(4)));

__device__ __forceinline__ u16 f2bf(float f) {
  unsigned u = __float_as_uint(f);
  u += 0x7fffu + ((u >> 16) & 1u);   // round-nearest-even
  return (u16)(u >> 16);
}
__device__ __forceinline__ float bf2f(u16 s) {
  return __uint_as_float(((unsigned)s) << 16);
}
__device__ __forceinline__ float gelu_f(float h) {
  return h * 0.5f * (1.f + tanhf(0.79788456f * h * (1.f + 0.044715f * h * h)));
}

// async global->LDS, 16B per lane. LDS dest must be wave-uniform-base + lane*16.
__device__ __forceinline__ void async_copy16(void* lds, const void* g) {
  __builtin_amdgcn_global_load_lds(
      (const __attribute__((address_space(1))) unsigned int*)g,
      (__attribute__((address_space(3))) unsigned int*)lds, 16, 0, 0);
}

// ---------------------------------------------------------------- transpose+bf16
// out[n][k] = bf16(W[k][n]);  W is [K][N] fp32 row-major, out is [N][K] bf16.
__global__ __launch_bounds__(256) void transpose_conv(
    const float* __restrict__ W, u16* __restrict__ out, int K, int N) {
  __shared__ float T[64][65];
  const int tid = threadIdx.x;
  const int n0 = blockIdx.x * 64, k0 = blockIdx.y * 64;
  const int r = tid >> 2, c4 = (tid & 3) * 16;
  const float* src = W + (size_t)(k0 + r) * N + n0 + c4;
#pragma unroll
  for (int i = 0; i < 16; i += 4) {
    float4 f = *(const float4*)(src + i);
    T[r][c4 + i + 0] = f.x; T[r][c4 + i + 1] = f.y;
    T[r][c4 + i + 2] = f.z; T[r][c4 + i + 3] = f.w;
  }
  __syncthreads();
  u16* dst = out + (size_t)(n0 + r) * K + k0 + c4;
#pragma unroll
  for (int half = 0; half < 2; ++half) {
    u16x8 o8;
#pragma unroll
    for (int i = 0; i < 8; ++i) o8[i] = f2bf(T[c4 + half * 8 + i][r]);
    *(u16x8*)(dst + half * 8) = o8;
  }
}

__global__ __launch_bounds__(256) void concat_bias(
    const float* __restrict__ bq, const float* __restrict__ bk,
    const float* __restrict__ bv, float* __restrict__ bqkv) {
  int i = blockIdx.x * 256 + threadIdx.x;
  if (i < 3072) {
    float v = (i < 1024) ? bq[i] : (i < 2048) ? bk[i - 1024] : bv[i - 2048];
    bqkv[i] = v;
  }
}

__global__ __launch_bounds__(256) void rope_tables(
    float* __restrict__ cosT, float* __restrict__ sinT) {
  int i = blockIdx.x * 256 + threadIdx.x;   // L_*32 total
  int pos = i >> 5, d = i & 31;
  float invf = powf(10000.f, -(float)d / 32.f);
  float a = (float)pos * invf;
  cosT[i] = cosf(a);
  sinT[i] = sinf(a);
}

// in-place RoPE on q,k halves of qkv[NR_][3072]; q additionally scaled by 1/8.
__global__ __launch_bounds__(256) void rope_apply(
    u16* __restrict__ qkv, const float* __restrict__ cosT,
    const float* __restrict__ sinT) {
  int i = blockIdx.x * 256 + threadIdx.x;  // NR_*1024 pairs
  int row = i >> 10;
  int c = i & 1023;
  int qk = c >> 9;             // 0=q, 1=k
  int hh = (c >> 5) & 15;
  int d  = c & 31;
  int pos = row & (L_ - 1);
  size_t base = (size_t)row * 3072 + qk * 1024 + hh * 64 + d;
  float v0 = bf2f(qkv[base]), v1 = bf2f(qkv[base + 32]);
  float co = cosT[pos * 32 + d], si = sinT[pos * 32 + d];
  float r0 = v0 * co - v1 * si;
  float r1 = v1 * co + v0 * si;
  if (qk == 0) { r0 *= 0.125f; r1 *= 0.125f; }  // fold 1/sqrt(HD) into Q
  qkv[base]      = f2bf(r0);
  qkv[base + 32] = f2bf(r1);
}

// ---------------------------------------------------------------- LayerNorm
__global__ __launch_bounds__(256) void ln_kernel(
    const float* __restrict__ x, const float* __restrict__ gm,
    const float* __restrict__ bt, u16* __restrict__ out) {
  const int row = blockIdx.x, tid = threadIdx.x;
  const float4 v = ((const float4*)(x + (size_t)row * D_))[tid];
  float s = v.x + v.y + v.z + v.w;
#pragma unroll
  for (int m = 1; m < 64; m <<= 1) s += __shfl_xor(s, m);
  __shared__ float red[4], red2[4];
  if ((tid & 63) == 0) red[tid >> 6] = s;
  __syncthreads();
  const float mean = (red[0] + red[1] + red[2] + red[3]) * (1.f / D_);
  float d0 = v.x - mean, d1 = v.y - mean, d2 = v.z - mean, d3 = v.w - mean;
  float sq = d0 * d0 + d1 * d1 + d2 * d2 + d3 * d3;
#pragma unroll
  for (int m = 1; m < 64; m <<= 1) sq += __shfl_xor(sq, m);
  if ((tid & 63) == 0) red2[tid >> 6] = sq;
  __syncthreads();
  const float var = (red2[0] + red2[1] + red2[2] + red2[3]) * (1.f / D_);
  const float rstd = rsqrtf(var + 1e-5f);
  const int c = tid * 4;
  u16x4 o;
  o[0] = f2bf(d0 * rstd * gm[c + 0] + bt[c + 0]);
  o[1] = f2bf(d1 * rstd * gm[c + 1] + bt[c + 1]);
  o[2] = f2bf(d2 * rstd * gm[c + 2] + bt[c + 2]);
  o[3] = f2bf(d3 * rstd * gm[c + 3] + bt[c + 3]);
  ((u16x4*)(out + (size_t)row * D_))[tid] = o;
}

// ---------------------------------------------------------------- GEMM (m97-style)
// C[M,N] = A[M,K] * Bt[N,K]^T (+bias[n]) ; EPI: 0=bf16, 1=gelu->bf16, 2=+resid->f32
template <int EPI>
__global__ __launch_bounds__(256) void gemm_bt(
    const u16* __restrict__ A, const u16* __restrict__ Bt,
    const float* __restrict__ bias, const float* __restrict__ resid,
    void* __restrict__ out, int M, int N, int K) {
  __shared__ u16 As[128 * 32];
  __shared__ u16 Bs[128 * 32];
  const int tid = threadIdx.x;
  const int l = tid & 63, wid = tid >> 6;
  const int m0 = blockIdx.y * 128, n0 = blockIdx.x * 128;
  const int wr = wid >> 1, wc = wid & 1;

  f32x4 acc[4][4];
#pragma unroll
  for (int mi = 0; mi < 4; ++mi)
#pragma unroll
    for (int ni = 0; ni < 4; ++ni) acc[mi][ni] = (f32x4){0.f, 0.f, 0.f, 0.f};

  for (int kb = 0; kb < K; kb += 32) {
#pragma unroll
    for (int r = 0; r < 2; ++r) {
      const int fo = r * 4096 + tid * 16;        // LDS byte offset
      const int row = fo >> 6, cb = fo & 63;     // tile row, col-bytes
      async_copy16((char*)As + fo, A + (size_t)(m0 + row) * K + kb + (cb >> 1));
      async_copy16((char*)Bs + fo, Bt + (size_t)(n0 + row) * K + kb + (cb >> 1));
    }
    __syncthreads();
    bf16x8 ag[4], bg[4];
#pragma unroll
    for (int mi = 0; mi < 4; ++mi) {
      int row = wr * 64 + mi * 16 + (l & 15);
      ag[mi] = *(const bf16x8*)((const char*)As + row * 64 + ((l >> 4) * 16));
    }
#pragma unroll
    for (int ni = 0; ni < 4; ++ni) {
      int row = wc * 64 + ni * 16 + (l & 15);
      bg[ni] = *(const bf16x8*)((const char*)Bs + row * 64 + ((l >> 4) * 16));
    }
#pragma unroll
    for (int mi = 0; mi < 4; ++mi)
#pragma unroll
      for (int ni = 0; ni < 4; ++ni)
        acc[mi][ni] = __builtin_amdgcn_mfma_f32_16x16x32_bf16(
            ag[mi], bg[ni], acc[mi][ni], 0, 0, 0);
    __syncthreads();
  }

  const int cl = l & 15, rq = l >> 4;
#pragma unroll
  for (int ni = 0; ni < 4; ++ni) {
    const int col = n0 + wc * 64 + ni * 16 + cl;
    const float bv = bias[col];
#pragma unroll
    for (int mi = 0; mi < 4; ++mi) {
#pragma unroll
      for (int j = 0; j < 4; ++j) {
        const int rowg = m0 + wr * 64 + mi * 16 + rq * 4 + j;
        float v = acc[mi][ni][j] + bv;
        if (EPI == 0) {
          ((u16*)out)[(size_t)rowg * N + col] = f2bf(v);
        } else if (EPI == 1) {
          ((u16*)out)[(size_t)rowg * N + col] = f2bf(gelu_f(v));
        } else {
          ((float*)out)[(size_t)rowg * N + col] =
              v + resid[(size_t)rowg * N + col];
        }
      }
    }
  }
}

// ---------------------------------------------------------------- flash attention
// qkv[NR_][3072] bf16 (q pre-scaled+roped, k roped). out[NR_][D_] bf16.
// grid: (L_/64, B_*H_); 4 waves, each owns 16 q rows. KV-block = 64.
__global__ __launch_bounds__(256) void attn_kernel(
    const u16* __restrict__ qkv, u16* __restrict__ o) {
  const int tid = threadIdx.x, l = tid & 63, wid = tid >> 6;
  const int q0 = blockIdx.x * 64;
  const int b = blockIdx.y >> 4, h = blockIdx.y & 15;
  __shared__ u16 Ks[64 * 64];
  __shared__ u16 Vt[64 * 64];
  __shared__ u16 Ps[4][16 * 64];

  // Q A-fragments (row = l&15 within wave's 16 rows)
  const int qrow_g = b * L_ + q0 + wid * 16 + (l & 15);
  const u16* qp = qkv + (size_t)qrow_g * 3072 + h * 64 + ((l >> 4) * 8);
  const bf16x8 qa0 = *(const bf16x8*)qp;
  const bf16x8 qa1 = *(const bf16x8*)(qp + 32);

  float m_[4], ls[4];
  f32x4 oa[4];
#pragma unroll
  for (int j = 0; j < 4; ++j) { m_[j] = -1e30f; ls[j] = 0.f; }
#pragma unroll
  for (int t = 0; t < 4; ++t) oa[t] = (f32x4){0.f, 0.f, 0.f, 0.f};

  const int kend = q0 + 64;
  for (int kb = 0; kb < kend; kb += 64) {
    // ---- stage K (swizzled) and V^T (swizzled) into LDS
#pragma unroll
    for (int r2 = 0; r2 < 2; ++r2) {
      const int idx = r2 * 256 + tid;
      const int row = idx >> 3, c8 = (idx & 7) * 8;
      const size_t gbase = (size_t)(b * L_ + kb + row) * 3072 + h * 64;
      u16x8 kv = *(const u16x8*)(qkv + gbase + 1024 + c8);
      *(u16x8*)((char*)Ks + row * 128 + ((c8 * 2) ^ ((row & 7) << 4))) = kv;
      u16x8 vv = *(const u16x8*)(qkv + gbase + 2048 + c8);
#pragma unroll
      for (int i = 0; i < 8; ++i) {
        const int d = c8 + i;
        *(u16*)((char*)Vt + d * 128 + ((row * 2) ^ ((d & 7) << 4))) = vv[i];
      }
    }
    __syncthreads();

    // ---- S = Q K^T (already scaled), causal mask
    float p[4][4];
#pragma unroll
    for (int t = 0; t < 4; ++t) {
      f32x4 s = (f32x4){0.f, 0.f, 0.f, 0.f};
#pragma unroll
      for (int dc = 0; dc < 2; ++dc) {
        const int row = t * 16 + (l & 15);
        const int de = dc * 32 + ((l >> 4) * 8);
        bf16x8 kf = *(const bf16x8*)((char*)Ks + row * 128 +
                                     ((de * 2) ^ ((row & 7) << 4)));
        s = __builtin_amdgcn_mfma_f32_16x16x32_bf16(dc ? qa1 : qa0, kf, s, 0, 0, 0);
      }
      const int kcol = kb + t * 16 + (l & 15);
      const int qrow = q0 + wid * 16 + ((l >> 4) << 2);
#pragma unroll
      for (int j = 0; j < 4; ++j)
        p[t][j] = (kcol <= qrow + j) ? s[j] : -1e30f;
    }

    // ---- online softmax (rows live in 16-lane groups)
#pragma unroll
    for (int j = 0; j < 4; ++j) {
      float pm = fmaxf(fmaxf(p[0][j], p[1][j]), fmaxf(p[2][j], p[3][j]));
      pm = fmaxf(pm, __shfl_xor(pm, 1));
      pm = fmaxf(pm, __shfl_xor(pm, 2));
      pm = fmaxf(pm, __shfl_xor(pm, 4));
      pm = fmaxf(pm, __shfl_xor(pm, 8));
      const float mn = fmaxf(m_[j], pm);
      const float sc = __expf(m_[j] - mn);
      float rs = 0.f;
#pragma unroll
      for (int t = 0; t < 4; ++t) { p[t][j] = __expf(p[t][j] - mn); rs += p[t][j]; }
      rs += __shfl_xor(rs, 1);
      rs += __shfl_xor(rs, 2);
      rs += __shfl_xor(rs, 4);
      rs += __shfl_xor(rs, 8);
      ls[j] = ls[j] * sc + rs;
      m_[j] = mn;
#pragma unroll
      for (int t = 0; t < 4; ++t) oa[t][j] *= sc;
    }

    // ---- P -> LDS (bf16, swizzled)
    const int qr = (l >> 4) << 2;
#pragma unroll
    for (int t = 0; t < 4; ++t)
#pragma unroll
      for (int j = 0; j < 4; ++j) {
        const int rr = qr + j, cc = t * 16 + (l & 15);
        *(u16*)((char*)&Ps[wid][0] + rr * 128 + ((cc * 2) ^ ((rr & 7) << 4))) =
            f2bf(p[t][j]);
      }
    __syncthreads();

    // ---- O += P V
#pragma unroll
    for (int t = 0; t < 4; ++t) {
#pragma unroll
      for (int kc = 0; kc < 2; ++kc) {
        const int pr = l & 15, ke = kc * 32 + ((l >> 4) * 8);
        bf16x8 pf = *(const bf16x8*)((char*)&Ps[wid][0] + pr * 128 +
                                     ((ke * 2) ^ ((pr & 7) << 4)));
        const int vr = t * 16 + (l & 15);
        bf16x8 vf = *(const bf16x8*)((char*)Vt + vr * 128 +
                                     ((ke * 2) ^ ((vr & 7) << 4)));
        oa[t] = __builtin_amdgcn_mfma_f32_16x16x32_bf16(pf, vf, oa[t], 0, 0, 0);
      }
    }
    __syncthreads();
  }

  // ---- normalize + store
#pragma unroll
  for (int j = 0; j < 4; ++j) {
    const float inv = 1.f / ls[j];
    const int rowg = b * L_ + q0 + wid * 16 + ((l >> 4) << 2) + j;
    u16* op = o + (size_t)rowg * D_ + h * 64 + (l & 15);
#pragma unroll
    for (int t = 0; t < 4; ++t) op[t * 16] = f2bf(oa[t][j] * inv);
  }
}

// ---------------------------------------------------------------- launch
extern "C" void kernel_launch(void* const* d_in, const int* in_sizes, int n_in,
                              void* d_out, int out_size, void* d_ws, size_t ws_size,
                              hipStream_t stream) {
  (void)in_sizes; (void)n_in; (void)out_size; (void)ws_size;
  const float* x    = (const float*)d_in[0];
  const float* Wq   = (const float*)d_in[2];
  const float* bq   = (const float*)d_in[3];
  const float* Wk   = (const float*)d_in[4];
  const float* bk   = (const float*)d_in[5];
  const float* Wv   = (const float*)d_in[6];
  const float* bv   = (const float*)d_in[7];
  const float* Wo   = (const float*)d_in[8];
  const float* bo   = (const float*)d_in[9];
  const float* ln1g = (const float*)d_in[10];
  const float* ln1b = (const float*)d_in[11];
  const float* W1   = (const float*)d_in[12];
  const float* b1   = (const float*)d_in[13];
  const float* W2   = (const float*)d_in[14];
  const float* b2   = (const float*)d_in[15];
  const float* ln2g = (const float*)d_in[16];
  const float* ln2b = (const float*)d_in[17];
  float* out = (float*)d_out;
  char* ws = (char*)d_ws;

  u16*   wqkvT = (u16*)(ws + 0);              // [3072][1024] bf16
  u16*   woT   = (u16*)(ws + 6291456);        // [1024][1024]
  u16*   w1T   = (u16*)(ws + 8388608);        // [4096][1024]
  u16*   w2T   = (u16*)(ws + 16777216);       // [1024][4096]
  float* bqkv  = (float*)(ws + 25165824);     // [3072]
  float* cosT  = (float*)(ws + 25178112);     // [2048][32]
  float* sinT  = (float*)(ws + 25440256);
  float* x2    = (float*)(ws + 25702400);     // [4096][1024] f32
  u16*   lnbuf = (u16*)(ws + 42479616);       // [4096][1024] bf16 (ln1 then ln2)
  u16*   qkv   = (u16*)(ws + 50868224);       // [4096][3072] bf16
  u16*   attnO = (u16*)(ws + 76034048);       // [4096][1024] bf16
  u16*   hbuf  = qkv;                         // [4096][4096] bf16 overlays qkv+attnO

  const dim3 blk(256);
  // weights -> B^T bf16
  transpose_conv<<<dim3(16, 16), blk, 0, stream>>>(Wq, wqkvT, 1024, 1024);
  transpose_conv<<<dim3(16, 16), blk, 0, stream>>>(Wk, wqkvT + 1024 * 1024, 1024, 1024);
  transpose_conv<<<dim3(16, 16), blk, 0, stream>>>(Wv, wqkvT + 2048 * 1024, 1024, 1024);
  transpose_conv<<<dim3(16, 16), blk, 0, stream>>>(Wo, woT, 1024, 1024);
  transpose_conv<<<dim3(64, 16), blk, 0, stream>>>(W1, w1T, 1024, 4096);
  transpose_conv<<<dim3(16, 64), blk, 0, stream>>>(W2, w2T, 4096, 1024);
  concat_bias<<<12, blk, 0, stream>>>(bq, bk, bv, bqkv);
  rope_tables<<<256, blk, 0, stream>>>(cosT, sinT);

  // LN1 -> fused QKV GEMM -> RoPE -> attention
  ln_kernel<<<NR_, blk, 0, stream>>>(x, ln1g, ln1b, lnbuf);
  gemm_bt<0><<<dim3(24, 32), blk, 0, stream>>>(lnbuf, wqkvT, bqkv, nullptr,
                                               qkv, NR_, 3072, 1024);
  rope_apply<<<16384, blk, 0, stream>>>(qkv, cosT, sinT);
  attn_kernel<<<dim3(32, 32), blk, 0, stream>>>(qkv, attnO);

  // O-proj + residual (f32) -> LN2 -> MLP
  gemm_bt<2><<<dim3(8, 32), blk, 0, stream>>>(attnO, woT, bo, x, x2,
                                              NR_, 1024, 1024);
  ln_kernel<<<NR_, blk, 0, stream>>>(x2, ln2g, ln2b, lnbuf);
  gemm_bt<1><<<dim3(32, 32), blk, 0, stream>>>(lnbuf, w1T, b1, nullptr,
                                               hbuf, NR_, 4096, 1024);
  gemm_bt<2><<<dim3(8, 32), blk, 0, stream>>>(hbuf, w2T, b2, x2, out,
                                              NR_, 1024, 4096);
}

// Round 2
// 549.811 us; speedup vs baseline: 1.0368x; 1.0368x over previous
//
#include <hip/hip_runtime.h>
#include <math.h>

#define B_  2
#define L_  2048
#define D_  1024
#define H_  16
#define HD_ 64
#define DF_ 4096
#define NR_ 4096   // B_*L_

typedef __bf16 bf16_t;
typedef bf16_t bf16x8 __attribute__((ext_vector_type(8)));
typedef float  f32x4  __attribute__((ext_vector_type(4)));
typedef unsigned short u16;
typedef u16 u16x8 __attribute__((ext_vector_type(8)));
typedef u16 u16x4 __attribute__((ext_vector_type(4)));

__device__ __forceinline__ u16 f2bf(float f) {
  unsigned u = __float_as_uint(f);
  u += 0x7fffu + ((u >> 16) & 1u);   // round-nearest-even
  return (u16)(u >> 16);
}
__device__ __forceinline__ float bf2f(u16 s) {
  return __uint_as_float(((unsigned)s) << 16);
}
__device__ __forceinline__ float gelu_f(float h) {
  return h * 0.5f * (1.f + tanhf(0.79788456f * h * (1.f + 0.044715f * h * h)));
}

// async global->LDS, 16B per lane. LDS dest must be wave-uniform-base + lane*16.
__device__ __forceinline__ void async_copy16(void* lds, const void* g) {
  __builtin_amdgcn_global_load_lds(
      (const __attribute__((address_space(1))) unsigned int*)g,
      (__attribute__((address_space(3))) unsigned int*)lds, 16, 0, 0);
}

// ---------------------------------------------------------------- transpose+bf16
// out[n][k] = bf16(W[k][n]);  W is [K][N] fp32 row-major, out is [N][K] bf16.
__global__ __launch_bounds__(256) void transpose_conv(
    const float* __restrict__ W, u16* __restrict__ out, int K, int N) {
  __shared__ float T[64][65];
  const int tid = threadIdx.x;
  const int n0 = blockIdx.x * 64, k0 = blockIdx.y * 64;
  const int r = tid >> 2, c4 = (tid & 3) * 16;
  const float* src = W + (size_t)(k0 + r) * N + n0 + c4;
#pragma unroll
  for (int i = 0; i < 16; i += 4) {
    float4 f = *(const float4*)(src + i);
    T[r][c4 + i + 0] = f.x; T[r][c4 + i + 1] = f.y;
    T[r][c4 + i + 2] = f.z; T[r][c4 + i + 3] = f.w;
  }
  __syncthreads();
  u16* dst = out + (size_t)(n0 + r) * K + k0 + c4;
#pragma unroll
  for (int half = 0; half < 2; ++half) {
    u16x8 o8;
#pragma unroll
    for (int i = 0; i < 8; ++i) o8[i] = f2bf(T[c4 + half * 8 + i][r]);
    *(u16x8*)(dst + half * 8) = o8;
  }
}

__global__ __launch_bounds__(256) void concat_bias(
    const float* __restrict__ bq, const float* __restrict__ bk,
    const float* __restrict__ bv, float* __restrict__ bqkv) {
  int i = blockIdx.x * 256 + threadIdx.x;
  if (i < 3072) {
    float v = (i < 1024) ? bq[i] : (i < 2048) ? bk[i - 1024] : bv[i - 2048];
    bqkv[i] = v;
  }
}

__global__ __launch_bounds__(256) void rope_tables(
    float* __restrict__ cosT, float* __restrict__ sinT) {
  int i = blockIdx.x * 256 + threadIdx.x;   // L_*32 total
  int pos = i >> 5, d = i & 31;
  float invf = powf(10000.f, -(float)d / 32.f);
  float a = (float)pos * invf;
  cosT[i] = cosf(a);
  sinT[i] = sinf(a);
}

// in-place RoPE on q,k halves of qkv[NR_][3072]; q additionally scaled by 1/8.
// One thread per 8 contiguous d in [0,32): handles (d, d+32) pairs vectorized.
__global__ __launch_bounds__(256) void rope_apply(
    u16* __restrict__ qkv, const float* __restrict__ cosT,
    const float* __restrict__ sinT) {
  int i = blockIdx.x * 256 + threadIdx.x;  // NR_*2*16*4 = 524288 threads
  int d0 = (i & 3) * 8;
  int hh = (i >> 2) & 15;
  int qk = (i >> 6) & 1;
  int row = i >> 7;
  int pos = row & (L_ - 1);
  size_t base = (size_t)row * 3072 + qk * 1024 + hh * 64 + d0;
  u16x8 a = *(const u16x8*)(qkv + base);
  u16x8 bb = *(const u16x8*)(qkv + base + 32);
  float4 c0 = *(const float4*)(cosT + pos * 32 + d0);
  float4 c1 = *(const float4*)(cosT + pos * 32 + d0 + 4);
  float4 s0 = *(const float4*)(sinT + pos * 32 + d0);
  float4 s1 = *(const float4*)(sinT + pos * 32 + d0 + 4);
  const float qs = qk ? 1.f : 0.125f;   // fold 1/sqrt(HD) into Q
  u16x8 ra, rb;
#pragma unroll
  for (int j = 0; j < 8; ++j) {
    float co = (j < 4) ? ((const float*)&c0)[j] : ((const float*)&c1)[j - 4];
    float si = (j < 4) ? ((const float*)&s0)[j] : ((const float*)&s1)[j - 4];
    float v0 = bf2f(a[j]), v1 = bf2f(bb[j]);
    ra[j] = f2bf((v0 * co - v1 * si) * qs);
    rb[j] = f2bf((v1 * co + v0 * si) * qs);
  }
  *(u16x8*)(qkv + base) = ra;
  *(u16x8*)(qkv + base + 32) = rb;
}

// ---------------------------------------------------------------- V transpose
// vt[bh][d][seq] <- qkv V-part.  Reads coalesced (128B/lane-group), writes 16B/lane.
__global__ __launch_bounds__(256) void v_transpose(
    const u16* __restrict__ qkv, u16* __restrict__ vt) {
  const int tid = threadIdx.x;
  const int d = tid & 63, sub = tid >> 6;
  const int s0 = (blockIdx.x * 4 + sub) * 8;
  const int bh = blockIdx.y, b = bh >> 4, h = bh & 15;
  u16x8 o;
#pragma unroll
  for (int i = 0; i < 8; ++i)
    o[i] = qkv[(size_t)(b * L_ + s0 + i) * 3072 + 2048 + h * 64 + d];
  *(u16x8*)(vt + ((size_t)bh * 64 + d) * 2048 + s0) = o;
}

// ---------------------------------------------------------------- LayerNorm
__global__ __launch_bounds__(256) void ln_kernel(
    const float* __restrict__ x, const float* __restrict__ gm,
    const float* __restrict__ bt, u16* __restrict__ out) {
  const int row = blockIdx.x, tid = threadIdx.x;
  const float4 v = ((const float4*)(x + (size_t)row * D_))[tid];
  float s = v.x + v.y + v.z + v.w;
#pragma unroll
  for (int m = 1; m < 64; m <<= 1) s += __shfl_xor(s, m);
  __shared__ float red[4], red2[4];
  if ((tid & 63) == 0) red[tid >> 6] = s;
  __syncthreads();
  const float mean = (red[0] + red[1] + red[2] + red[3]) * (1.f / D_);
  float d0 = v.x - mean, d1 = v.y - mean, d2 = v.z - mean, d3 = v.w - mean;
  float sq = d0 * d0 + d1 * d1 + d2 * d2 + d3 * d3;
#pragma unroll
  for (int m = 1; m < 64; m <<= 1) sq += __shfl_xor(sq, m);
  if ((tid & 63) == 0) red2[tid >> 6] = sq;
  __syncthreads();
  const float var = (red2[0] + red2[1] + red2[2] + red2[3]) * (1.f / D_);
  const float rstd = rsqrtf(var + 1e-5f);
  const int c = tid * 4;
  u16x4 o;
  o[0] = f2bf(d0 * rstd * gm[c + 0] + bt[c + 0]);
  o[1] = f2bf(d1 * rstd * gm[c + 1] + bt[c + 1]);
  o[2] = f2bf(d2 * rstd * gm[c + 2] + bt[c + 2]);
  o[3] = f2bf(d3 * rstd * gm[c + 3] + bt[c + 3]);
  ((u16x4*)(out + (size_t)row * D_))[tid] = o;
}

// ---------------------------------------------------------------- GEMM (m97-style)
// C[M,N] = A[M,K] * Bt[N,K]^T (+bias[n]) ; EPI: 0=bf16, 1=gelu->bf16, 2=+resid->f32
template <int EPI>
__global__ __launch_bounds__(256) void gemm_bt(
    const u16* __restrict__ A, const u16* __restrict__ Bt,
    const float* __restrict__ bias, const float* __restrict__ resid,
    void* __restrict__ out, int M, int N, int K) {
  __shared__ u16 As[128 * 32];
  __shared__ u16 Bs[128 * 32];
  const int tid = threadIdx.x;
  const int l = tid & 63, wid = tid >> 6;
  const int m0 = blockIdx.y * 128, n0 = blockIdx.x * 128;
  const int wr = wid >> 1, wc = wid & 1;

  f32x4 acc[4][4];
#pragma unroll
  for (int mi = 0; mi < 4; ++mi)
#pragma unroll
    for (int ni = 0; ni < 4; ++ni) acc[mi][ni] = (f32x4){0.f, 0.f, 0.f, 0.f};

  for (int kb = 0; kb < K; kb += 32) {
#pragma unroll
    for (int r = 0; r < 2; ++r) {
      const int fo = r * 4096 + tid * 16;        // LDS byte offset
      const int row = fo >> 6, cb = fo & 63;     // tile row, col-bytes
      async_copy16((char*)As + fo, A + (size_t)(m0 + row) * K + kb + (cb >> 1));
      async_copy16((char*)Bs + fo, Bt + (size_t)(n0 + row) * K + kb + (cb >> 1));
    }
    __syncthreads();
    bf16x8 ag[4], bg[4];
#pragma unroll
    for (int mi = 0; mi < 4; ++mi) {
      int row = wr * 64 + mi * 16 + (l & 15);
      ag[mi] = *(const bf16x8*)((const char*)As + row * 64 + ((l >> 4) * 16));
    }
#pragma unroll
    for (int ni = 0; ni < 4; ++ni) {
      int row = wc * 64 + ni * 16 + (l & 15);
      bg[ni] = *(const bf16x8*)((const char*)Bs + row * 64 + ((l >> 4) * 16));
    }
#pragma unroll
    for (int mi = 0; mi < 4; ++mi)
#pragma unroll
      for (int ni = 0; ni < 4; ++ni)
        acc[mi][ni] = __builtin_amdgcn_mfma_f32_16x16x32_bf16(
            ag[mi], bg[ni], acc[mi][ni], 0, 0, 0);
    __syncthreads();
  }

  const int cl = l & 15, rq = l >> 4;
#pragma unroll
  for (int ni = 0; ni < 4; ++ni) {
    const int col = n0 + wc * 64 + ni * 16 + cl;
    const float bv = bias[col];
#pragma unroll
    for (int mi = 0; mi < 4; ++mi) {
#pragma unroll
      for (int j = 0; j < 4; ++j) {
        const int rowg = m0 + wr * 64 + mi * 16 + rq * 4 + j;
        float v = acc[mi][ni][j] + bv;
        if (EPI == 0) {
          ((u16*)out)[(size_t)rowg * N + col] = f2bf(v);
        } else if (EPI == 1) {
          ((u16*)out)[(size_t)rowg * N + col] = f2bf(gelu_f(v));
        } else {
          ((float*)out)[(size_t)rowg * N + col] =
              v + resid[(size_t)rowg * N + col];
        }
      }
    }
  }
}

// ---------------------------------------------------------------- flash attention
// Barrier-free: K frags direct from global (L2), V frags from vt[bh][d][seq],
// P per-wave in LDS. 4 waves x 16 q-rows = 64 q-rows/block. KV-block = 64.
__global__ __launch_bounds__(256, 4) void attn_kernel(
    const u16* __restrict__ qkv, const u16* __restrict__ vt,
    u16* __restrict__ o) {
  const int tid = threadIdx.x, l = tid & 63, wid = tid >> 6;
  // XCD-aware decomposition: 8 XCDs x (4 bh x 32 qblk); heavy qblk first.
  const int id = blockIdx.x;
  const int seq = id >> 3, xcd = id & 7;
  const int bh = xcd * 4 + (seq & 3);
  const int qblk = 31 - (seq >> 2);
  const int b = bh >> 4, h = bh & 15;
  const int q0 = qblk * 64;
  __shared__ u16 Ps[4][16 * 64];   // per-wave private P, swizzled

  // Q A-fragments (row = l&15 within wave's 16 rows); q pre-scaled + roped.
  const int qrow_g = b * L_ + q0 + wid * 16 + (l & 15);
  const u16* qp = qkv + (size_t)qrow_g * 3072 + h * 64 + ((l >> 4) * 8);
  const bf16x8 qa0 = *(const bf16x8*)qp;
  const bf16x8 qa1 = *(const bf16x8*)(qp + 32);

  // lane-invariant-per-tile base pointers
  const u16* kbase = qkv + (size_t)(b * L_ + (l & 15)) * 3072 + 1024 + h * 64 +
                     ((l >> 4) * 8);
  const u16* vbase = vt + ((size_t)bh * 64 + (l & 15)) * 2048 + ((l >> 4) * 8);

  float m_[4], ls[4];
  f32x4 oa[4];
#pragma unroll
  for (int j = 0; j < 4; ++j) { m_[j] = -1e30f; ls[j] = 0.f; }
#pragma unroll
  for (int t = 0; t < 4; ++t) oa[t] = (f32x4){0.f, 0.f, 0.f, 0.f};

  char* const psw = (char*)&Ps[wid][0];
  const int rq4 = (l >> 4) << 2;

  for (int kb = 0; kb <= q0; kb += 64) {
    const bool diag = (kb == q0);

    // ---- K fragments (8x dwordx4 from global, L2-resident)
    bf16x8 kf[4][2];
#pragma unroll
    for (int t = 0; t < 4; ++t) {
      const u16* kp = kbase + (size_t)(kb + t * 16) * 3072;
      kf[t][0] = *(const bf16x8*)kp;
      kf[t][1] = *(const bf16x8*)(kp + 32);
    }

    // ---- S = Q K^T (pre-scaled), mask only on diagonal tile
    float p[4][4];
#pragma unroll
    for (int t = 0; t < 4; ++t) {
      f32x4 s = (f32x4){0.f, 0.f, 0.f, 0.f};
      s = __builtin_amdgcn_mfma_f32_16x16x32_bf16(qa0, kf[t][0], s, 0, 0, 0);
      s = __builtin_amdgcn_mfma_f32_16x16x32_bf16(qa1, kf[t][1], s, 0, 0, 0);
      if (diag) {
        const int kcol = t * 16 + (l & 15);       // tile-relative
        const int qrow = wid * 16 + rq4;
#pragma unroll
        for (int j = 0; j < 4; ++j)
          p[t][j] = (kcol <= qrow + j) ? s[j] : -1e30f;
      } else {
#pragma unroll
        for (int j = 0; j < 4; ++j) p[t][j] = s[j];
      }
    }

    // ---- online softmax (rows live in 16-lane groups)
#pragma unroll
    for (int j = 0; j < 4; ++j) {
      float pm = fmaxf(fmaxf(p[0][j], p[1][j]), fmaxf(p[2][j], p[3][j]));
      pm = fmaxf(pm, __shfl_xor(pm, 1));
      pm = fmaxf(pm, __shfl_xor(pm, 2));
      pm = fmaxf(pm, __shfl_xor(pm, 4));
      pm = fmaxf(pm, __shfl_xor(pm, 8));
      const float mn = fmaxf(m_[j], pm);
      const float sc = __expf(m_[j] - mn);
      float rs = 0.f;
#pragma unroll
      for (int t = 0; t < 4; ++t) { p[t][j] = __expf(p[t][j] - mn); rs += p[t][j]; }
      rs += __shfl_xor(rs, 1);
      rs += __shfl_xor(rs, 2);
      rs += __shfl_xor(rs, 4);
      rs += __shfl_xor(rs, 8);
      ls[j] = ls[j] * sc + rs;
      m_[j] = mn;
#pragma unroll
      for (int t = 0; t < 4; ++t) oa[t][j] *= sc;
    }

    // ---- P -> per-wave LDS (bf16, swizzled); no barrier needed
#pragma unroll
    for (int t = 0; t < 4; ++t)
#pragma unroll
      for (int j = 0; j < 4; ++j) {
        const int rr = rq4 + j, cc = t * 16 + (l & 15);
        *(u16*)(psw + rr * 128 + ((cc * 2) ^ ((rr & 7) << 4))) = f2bf(p[t][j]);
      }

    // ---- V fragments (8x dwordx4 from vt global)
    bf16x8 vf[4][2];
#pragma unroll
    for (int t = 0; t < 4; ++t) {
      const u16* vp = vbase + (size_t)t * 16 * 2048 + kb;
      vf[t][0] = *(const bf16x8*)vp;
      vf[t][1] = *(const bf16x8*)(vp + 32);
    }

    // ---- O += P V
#pragma unroll
    for (int kc = 0; kc < 2; ++kc) {
      const int pr = l & 15, ke = kc * 32 + ((l >> 4) * 8);
      bf16x8 pf = *(const bf16x8*)(psw + pr * 128 + ((ke * 2) ^ ((pr & 7) << 4)));
#pragma unroll
      for (int t = 0; t < 4; ++t)
        oa[t] = __builtin_amdgcn_mfma_f32_16x16x32_bf16(pf, vf[t][kc], oa[t], 0, 0, 0);
    }
  }

  // ---- normalize + store
#pragma unroll
  for (int j = 0; j < 4; ++j) {
    const float inv = 1.f / ls[j];
    const int rowg = b * L_ + q0 + wid * 16 + rq4 + j;
    u16* op = o + (size_t)rowg * D_ + h * 64 + (l & 15);
#pragma unroll
    for (int t = 0; t < 4; ++t) op[t * 16] = f2bf(oa[t][j] * inv);
  }
}

// ---------------------------------------------------------------- launch
extern "C" void kernel_launch(void* const* d_in, const int* in_sizes, int n_in,
                              void* d_out, int out_size, void* d_ws, size_t ws_size,
                              hipStream_t stream) {
  (void)in_sizes; (void)n_in; (void)out_size; (void)ws_size;
  const float* x    = (const float*)d_in[0];
  const float* Wq   = (const float*)d_in[2];
  const float* bq   = (const float*)d_in[3];
  const float* Wk   = (const float*)d_in[4];
  const float* bk   = (const float*)d_in[5];
  const float* Wv   = (const float*)d_in[6];
  const float* bv   = (const float*)d_in[7];
  const float* Wo   = (const float*)d_in[8];
  const float* bo   = (const float*)d_in[9];
  const float* ln1g = (const float*)d_in[10];
  const float* ln1b = (const float*)d_in[11];
  const float* W1   = (const float*)d_in[12];
  const float* b1   = (const float*)d_in[13];
  const float* W2   = (const float*)d_in[14];
  const float* b2   = (const float*)d_in[15];
  const float* ln2g = (const float*)d_in[16];
  const float* ln2b = (const float*)d_in[17];
  float* out = (float*)d_out;
  char* ws = (char*)d_ws;

  u16*   wqkvT = (u16*)(ws + 0);              // [3072][1024] bf16
  u16*   woT   = (u16*)(ws + 6291456);        // [1024][1024]
  u16*   w1T   = (u16*)(ws + 8388608);        // [4096][1024]
  u16*   w2T   = (u16*)(ws + 16777216);       // [1024][4096]
  float* bqkv  = (float*)(ws + 25165824);     // [3072]
  float* cosT  = (float*)(ws + 25178112);     // [2048][32]
  float* sinT  = (float*)(ws + 25440256);
  float* x2    = (float*)(ws + 25702400);     // [4096][1024] f32
  u16*   lnbuf = (u16*)(ws + 42479616);       // [4096][1024] bf16 (ln1/ln2)
  u16*   vtb   = lnbuf;                       // vt[32][64][2048] overlays lnbuf
  u16*   qkv   = (u16*)(ws + 50868224);       // [4096][3072] bf16
  u16*   attnO = (u16*)(ws + 76034048);       // [4096][1024] bf16
  u16*   hbuf  = qkv;                         // [4096][4096] bf16 overlays qkv+attnO

  const dim3 blk(256);
  // weights -> B^T bf16
  transpose_conv<<<dim3(16, 16), blk, 0, stream>>>(Wq, wqkvT, 1024, 1024);
  transpose_conv<<<dim3(16, 16), blk, 0, stream>>>(Wk, wqkvT + 1024 * 1024, 1024, 1024);
  transpose_conv<<<dim3(16, 16), blk, 0, stream>>>(Wv, wqkvT + 2048 * 1024, 1024, 1024);
  transpose_conv<<<dim3(16, 16), blk, 0, stream>>>(Wo, woT, 1024, 1024);
  transpose_conv<<<dim3(64, 16), blk, 0, stream>>>(W1, w1T, 1024, 4096);
  transpose_conv<<<dim3(16, 64), blk, 0, stream>>>(W2, w2T, 4096, 1024);
  concat_bias<<<12, blk, 0, stream>>>(bq, bk, bv, bqkv);
  rope_tables<<<256, blk, 0, stream>>>(cosT, sinT);

  // LN1 -> fused QKV GEMM -> RoPE -> V^T -> attention
  ln_kernel<<<NR_, blk, 0, stream>>>(x, ln1g, ln1b, lnbuf);
  gemm_bt<0><<<dim3(24, 32), blk, 0, stream>>>(lnbuf, wqkvT, bqkv, nullptr,
                                               qkv, NR_, 3072, 1024);
  rope_apply<<<2048, blk, 0, stream>>>(qkv, cosT, sinT);
  v_transpose<<<dim3(64, 32), blk, 0, stream>>>(qkv, vtb);
  attn_kernel<<<1024, blk, 0, stream>>>(qkv, vtb, attnO);

  // O-proj + residual (f32) -> LN2 -> MLP
  gemm_bt<2><<<dim3(8, 32), blk, 0, stream>>>(attnO, woT, bo, x, x2,
                                              NR_, 1024, 1024);
  ln_kernel<<<NR_, blk, 0, stream>>>(x2, ln2g, ln2b, lnbuf);
  gemm_bt<1><<<dim3(32, 32), blk, 0, stream>>>(lnbuf, w1T, b1, nullptr,
                                               hbuf, NR_, 4096, 1024);
  gemm_bt<2><<<dim3(8, 32), blk, 0, stream>>>(hbuf, w2T, b2, x2, out,
                                              NR_, 1024, 4096);
}